// Round 3
// baseline (1226.158 us; speedup 1.0000x reference)
//
#include <hip/hip_runtime.h>

#define HIDDEN 64
#define CF 8        // features per chunk
#define NCHUNK 8    // chunks (= XCD count)

// ---------- degree counting ----------
__global__ void degree_kernel(const int* __restrict__ src, const int* __restrict__ dst,
                              float* __restrict__ outdeg, int* __restrict__ indeg, int E) {
    int e = blockIdx.x * blockDim.x + threadIdx.x;
    if (e < E) {
        atomicAdd(&outdeg[src[e]], 1.0f);
        atomicAdd(&indeg[dst[e]], 1);
    }
}

__global__ void norm_kernel(float* __restrict__ nsrc, const int* __restrict__ indeg,
                            float* __restrict__ ndst, int N) {
    int i = blockIdx.x * blockDim.x + threadIdx.x;
    if (i < N) {
        nsrc[i] = rsqrtf(fmaxf(nsrc[i], 1.0f));
        ndst[i] = rsqrtf(fmaxf((float)indeg[i], 1.0f));
    }
}

// ---------- CSR build: scan over in-degrees ----------
__global__ void block_sum_kernel(const int* __restrict__ indeg, int* __restrict__ bsum, int N) {
    int t = threadIdx.x;
    int n = blockIdx.x * 256 + t;
    int v = (n < N) ? indeg[n] : 0;
#pragma unroll
    for (int off = 32; off > 0; off >>= 1) v += __shfl_down(v, off, 64);
    __shared__ int s[4];
    if ((t & 63) == 0) s[t >> 6] = v;
    __syncthreads();
    if (t == 0) bsum[blockIdx.x] = s[0] + s[1] + s[2] + s[3];
}

__global__ void scan_bsum_kernel(int* __restrict__ bsum, int B) {
    __shared__ int tmp[1024];
    int t = threadIdx.x;
    tmp[t] = (t < B) ? bsum[t] : 0;
    __syncthreads();
    for (int off = 1; off < 1024; off <<= 1) {
        int u = (t >= off) ? tmp[t - off] : 0;
        __syncthreads();
        tmp[t] += u;
        __syncthreads();
    }
    if (t < B) bsum[t] = (t > 0) ? tmp[t - 1] : 0;
}

__global__ void scan_final_kernel(const int* __restrict__ indeg, const int* __restrict__ bsum,
                                  int* __restrict__ cursor, int* __restrict__ row_ptr, int N) {
    __shared__ int tmp[256];
    int t = threadIdx.x;
    int n = blockIdx.x * 256 + t;
    int v = (n < N) ? indeg[n] : 0;
    tmp[t] = v;
    __syncthreads();
    for (int off = 1; off < 256; off <<= 1) {
        int u = (t >= off) ? tmp[t - off] : 0;
        __syncthreads();
        tmp[t] += u;
        __syncthreads();
    }
    if (n < N) {
        int incl = tmp[t] + bsum[blockIdx.x];
        row_ptr[n + 1] = incl;
        cursor[n] = incl - v;
    }
    if (n == 0) row_ptr[0] = 0;
}

__global__ void fill_csr_kernel(const int* __restrict__ src, const int* __restrict__ dst,
                                int* __restrict__ cursor, int* __restrict__ col, int E) {
    int e = blockIdx.x * blockDim.x + threadIdx.x;
    if (e < E) {
        int d = dst[e];
        int slot = atomicAdd(&cursor[d], 1);
        col[slot] = src[e];
    }
}

// ---------- embedding gather into chunked-transposed layout, pre-scaled by nsrc ----------
// hT[c][n][f] = emb[feats[n]][c*8+f] * nsrc[n];  idx = c*(N*8) + n*8 + f
__global__ void embed_kernel(const int* __restrict__ feats, const float* __restrict__ emb,
                             const float* __restrict__ nsrc, float* __restrict__ hT,
                             int N, int total) {
    int idx = blockIdx.x * blockDim.x + threadIdx.x;
    if (idx >= total) return;
    int c = idx / (N * CF);
    int r = idx - c * (N * CF);
    int n = r >> 3;
    int f = r & 7;
    hT[idx] = emb[feats[n] * HIDDEN + c * CF + f] * nsrc[n];
}

// ---------- dense 64x64 layer, chunked in/out: outT = inT @ W ----------
// one wave per node; lane l holds feature l (chunk=l>>3, f=l&7)
__global__ __launch_bounds__(256) void dense_kernel(const float* __restrict__ inT,
                                                    const float* __restrict__ W,
                                                    float* __restrict__ outT,
                                                    int N, int nstride) {
    __shared__ float Wsh[HIDDEN * HIDDEN];
    for (int i = threadIdx.x; i < HIDDEN * HIDDEN; i += blockDim.x) Wsh[i] = W[i];
    __syncthreads();

    int lane = threadIdx.x & 63;
    int warp = threadIdx.x >> 6;
    int c = lane >> 3, f = lane & 7;

    for (int n = blockIdx.x * 4 + warp; n < N; n += nstride) {
        float rv = inT[((size_t)c * N + n) * CF + f];
        float o = 0.0f;
#pragma unroll
        for (int k = 0; k < HIDDEN; k++) {
            o = fmaf(__shfl(rv, k, 64), Wsh[k * HIDDEN + lane], o);
        }
        outT[((size_t)c * N + n) * CF + f] = o;
    }
}

// ---------- chunked gather-SpMM with epilogue ----------
// chunk c = blockIdx & 7 (XCD-pinned under round-robin dispatch); wave = 8 edges x 8 features
// out[n][f] = (sum_{s in N(n)} tmpT[c][s][f]) * ndst[n] + b[c*8+f], optionally * nsrc[n]
__global__ __launch_bounds__(256) void spmm_kernel(const int* __restrict__ row_ptr,
                                                   const int* __restrict__ col,
                                                   const float* __restrict__ tmpT,
                                                   const float* __restrict__ ndst,
                                                   const float* __restrict__ nsrc,
                                                   const float* __restrict__ b,
                                                   float* __restrict__ outT,
                                                   int N, int nstride, int scale_out) {
    int lane = threadIdx.x & 63;
    int warp = threadIdx.x >> 6;
    int c = blockIdx.x & 7;
    int esub = lane >> 3;
    int f = lane & 7;
    const float* __restrict__ chunk = tmpT + (size_t)c * N * CF;
    float bias = b[c * CF + f];

    for (int n = (blockIdx.x >> 3) * 4 + warp; n < N; n += nstride) {
        int beg = row_ptr[n];
        int end = row_ptr[n + 1];
        float acc = 0.0f;
        for (int base = beg; base < end; base += 8) {
            int j = base + esub;
            float v = 0.0f;
            if (j < end) {
                int s = col[j];
                v = chunk[(size_t)s * CF + f];
            }
            acc += v;
        }
        acc += __shfl_xor(acc, 8, 64);
        acc += __shfl_xor(acc, 16, 64);
        acc += __shfl_xor(acc, 32, 64);
        float o = acc * ndst[n] + bias;
        if (scale_out) o *= nsrc[n];
        if (lane < 8) outT[((size_t)c * N + n) * CF + lane] = o;
    }
}

// ---------- sum pooling from chunked layout ----------
__global__ __launch_bounds__(256) void pool_kernel(const int* __restrict__ gids,
                                                   const float* __restrict__ hT,
                                                   float* __restrict__ pooled, int N) {
    int lane = threadIdx.x & 63;
    int n = blockIdx.x * 4 + (threadIdx.x >> 6);
    if (n < N) {
        int g = gids[n];
        float v = hT[((size_t)(lane >> 3) * N + n) * CF + (lane & 7)];
        atomicAdd(&pooled[(size_t)g * HIDDEN + lane], v);
    }
}

// ---------- regression head ----------
__global__ __launch_bounds__(256) void head_kernel(const float* __restrict__ pooled,
                                                   const float* __restrict__ Wreg,
                                                   float* __restrict__ out, int G) {
    int lane = threadIdx.x & 63;
    int g = blockIdx.x * (blockDim.x >> 6) + (threadIdx.x >> 6);
    if (g < G) {
        float v = pooled[(size_t)g * HIDDEN + lane] * Wreg[lane];
#pragma unroll
        for (int off = 32; off > 0; off >>= 1) v += __shfl_down(v, off, 64);
        if (lane == 0) out[g] = v;
    }
}

extern "C" void kernel_launch(void* const* d_in, const int* in_sizes, int n_in,
                              void* d_out, int out_size, void* d_ws, size_t ws_size,
                              hipStream_t stream) {
    const int*   feats = (const int*)d_in[0];
    const int*   src   = (const int*)d_in[1];
    const int*   dst   = (const int*)d_in[2];
    const int*   gids  = (const int*)d_in[3];
    const float* emb   = (const float*)d_in[5];
    const float* Ws    = (const float*)d_in[6];
    const float* bs    = (const float*)d_in[7];
    const float* Wreg  = (const float*)d_in[8];
    float* out = (float*)d_out;

    int N = in_sizes[0];
    int E = in_sizes[1];
    const int G = 512;
    int NB = (N + 255) / 256;

    char* p = (char*)d_ws;
    float* nsrc    = (float*)p;  p += (size_t)N * 4;   // zeroed
    int*   indeg   = (int*)p;    p += (size_t)N * 4;   // zeroed
    float* ndst    = (float*)p;  p += (size_t)N * 4;
    int*   cursor  = (int*)p;    p += (size_t)N * 4;
    int*   row_ptr = (int*)p;    p += (size_t)(N + 1) * 4;
    int*   bsum    = (int*)p;    p += 1024 * 4;
    int*   col     = (int*)p;    p += (size_t)E * 4;
    p = (char*)(((uintptr_t)p + 255) & ~(uintptr_t)255);
    float* hbuf    = (float*)p;  p += (size_t)N * HIDDEN * 4;   // chunked layout
    float* tmp     = (float*)p;  p += (size_t)N * HIDDEN * 4;   // chunked layout
    float* pooled  = (float*)p;  p += (size_t)G * HIDDEN * 4;

    hipMemsetAsync(nsrc, 0, (size_t)N * 8, stream);
    hipMemsetAsync(pooled, 0, (size_t)G * HIDDEN * 4, stream);

    degree_kernel<<<(E + 255) / 256, 256, 0, stream>>>(src, dst, nsrc, indeg, E);
    norm_kernel<<<NB, 256, 0, stream>>>(nsrc, indeg, ndst, N);

    block_sum_kernel<<<NB, 256, 0, stream>>>(indeg, bsum, N);
    scan_bsum_kernel<<<1, 1024, 0, stream>>>(bsum, NB);
    scan_final_kernel<<<NB, 256, 0, stream>>>(indeg, bsum, cursor, row_ptr, N);
    fill_csr_kernel<<<(E + 255) / 256, 256, 0, stream>>>(src, dst, cursor, col, E);

    int total = N * HIDDEN;
    embed_kernel<<<(total + 255) / 256, 256, 0, stream>>>(feats, emb, nsrc, hbuf, N, total);

    const int GB_DENSE = 2048;                 // blocks for dense (4 waves each)
    const int GB_SPMM  = 2048;                 // per-chunk block groups
    int dstride = GB_DENSE * 4;
    int sstride = GB_SPMM * 4;

    for (int l = 0; l < 3; l++) {
        dense_kernel<<<GB_DENSE, 256, 0, stream>>>(hbuf, Ws + l * HIDDEN * HIDDEN,
                                                   tmp, N, dstride);
        spmm_kernel<<<NCHUNK * GB_SPMM, 256, 0, stream>>>(row_ptr, col, tmp, ndst, nsrc,
                                                          bs + l * HIDDEN, hbuf,
                                                          N, sstride, (l < 2) ? 1 : 0);
    }

    pool_kernel<<<(N + 3) / 4, 256, 0, stream>>>(gids, hbuf, pooled, N);
    head_kernel<<<(G + 3) / 4, 256, 0, stream>>>(pooled, Wreg, out, G);
}

// Round 4
// 1164.911 us; speedup vs baseline: 1.0526x; 1.0526x over previous
//
#include <hip/hip_runtime.h>

#define HIDDEN 64
#define CF 8        // features per chunk
#define NCHUNK 8    // chunks (= XCD count)

// ---------- degree counting ----------
__global__ void degree_kernel(const int* __restrict__ src, const int* __restrict__ dst,
                              float* __restrict__ outdeg, int* __restrict__ indeg, int E) {
    int e = blockIdx.x * blockDim.x + threadIdx.x;
    if (e < E) {
        atomicAdd(&outdeg[src[e]], 1.0f);
        atomicAdd(&indeg[dst[e]], 1);
    }
}

__global__ void norm_kernel(float* __restrict__ nsrc, const int* __restrict__ indeg,
                            float* __restrict__ ndst, int N) {
    int i = blockIdx.x * blockDim.x + threadIdx.x;
    if (i < N) {
        nsrc[i] = rsqrtf(fmaxf(nsrc[i], 1.0f));
        ndst[i] = rsqrtf(fmaxf((float)indeg[i], 1.0f));
    }
}

// ---------- CSR build: scan over in-degrees ----------
__global__ void block_sum_kernel(const int* __restrict__ indeg, int* __restrict__ bsum, int N) {
    int t = threadIdx.x;
    int n = blockIdx.x * 256 + t;
    int v = (n < N) ? indeg[n] : 0;
#pragma unroll
    for (int off = 32; off > 0; off >>= 1) v += __shfl_down(v, off, 64);
    __shared__ int s[4];
    if ((t & 63) == 0) s[t >> 6] = v;
    __syncthreads();
    if (t == 0) bsum[blockIdx.x] = s[0] + s[1] + s[2] + s[3];
}

__global__ void scan_bsum_kernel(int* __restrict__ bsum, int B) {
    __shared__ int tmp[1024];
    int t = threadIdx.x;
    tmp[t] = (t < B) ? bsum[t] : 0;
    __syncthreads();
    for (int off = 1; off < 1024; off <<= 1) {
        int u = (t >= off) ? tmp[t - off] : 0;
        __syncthreads();
        tmp[t] += u;
        __syncthreads();
    }
    if (t < B) bsum[t] = (t > 0) ? tmp[t - 1] : 0;
}

__global__ void scan_final_kernel(const int* __restrict__ indeg, const int* __restrict__ bsum,
                                  int* __restrict__ cursor, int* __restrict__ row_ptr, int N) {
    __shared__ int tmp[256];
    int t = threadIdx.x;
    int n = blockIdx.x * 256 + t;
    int v = (n < N) ? indeg[n] : 0;
    tmp[t] = v;
    __syncthreads();
    for (int off = 1; off < 256; off <<= 1) {
        int u = (t >= off) ? tmp[t - off] : 0;
        __syncthreads();
        tmp[t] += u;
        __syncthreads();
    }
    if (n < N) {
        int incl = tmp[t] + bsum[blockIdx.x];
        row_ptr[n + 1] = incl;
        cursor[n] = incl - v;
    }
    if (n == 0) row_ptr[0] = 0;
}

__global__ void fill_csr_kernel(const int* __restrict__ src, const int* __restrict__ dst,
                                int* __restrict__ cursor, int* __restrict__ col, int E) {
    int e = blockIdx.x * blockDim.x + threadIdx.x;
    if (e < E) {
        int d = dst[e];
        int slot = atomicAdd(&cursor[d], 1);
        col[slot] = src[e];
    }
}

// ---------- embedding gather into chunked-transposed layout, pre-scaled by nsrc ----------
__global__ void embed_kernel(const int* __restrict__ feats, const float* __restrict__ emb,
                             const float* __restrict__ nsrc, float* __restrict__ hT,
                             int N, int total) {
    int idx = blockIdx.x * blockDim.x + threadIdx.x;
    if (idx >= total) return;
    int c = idx / (N * CF);
    int r = idx - c * (N * CF);
    int n = r >> 3;
    int f = r & 7;
    hT[idx] = emb[feats[n] * HIDDEN + c * CF + f] * nsrc[n];
}

// ---------- dense 64x64 layer, chunked in/out: outT = inT @ W ----------
__global__ __launch_bounds__(256) void dense_kernel(const float* __restrict__ inT,
                                                    const float* __restrict__ W,
                                                    float* __restrict__ outT,
                                                    int N, int nstride) {
    __shared__ float Wsh[HIDDEN * HIDDEN];
    for (int i = threadIdx.x; i < HIDDEN * HIDDEN; i += blockDim.x) Wsh[i] = W[i];
    __syncthreads();

    int lane = threadIdx.x & 63;
    int warp = threadIdx.x >> 6;
    int c = lane >> 3, f = lane & 7;

    for (int n = blockIdx.x * 4 + warp; n < N; n += nstride) {
        float rv = inT[((size_t)c * N + n) * CF + f];
        float o = 0.0f;
#pragma unroll
        for (int k = 0; k < HIDDEN; k++) {
            o = fmaf(__shfl(rv, k, 64), Wsh[k * HIDDEN + lane], o);
        }
        outT[((size_t)c * N + n) * CF + f] = o;
    }
}

// ---------- chunked gather-SpMM, latency-pipelined ----------
// chunk c = blockIdx & 7 (XCD-pinned under round-robin dispatch).
// Per node: one coalesced 64-wide col load; 8 independent predicated gathers
// (8 edges x 8 features each); next node's row_ptr/col prefetched before
// consuming current gathers.
__global__ __launch_bounds__(256) void spmm_kernel(const int* __restrict__ row_ptr,
                                                   const int* __restrict__ col,
                                                   const float* __restrict__ tmpT,
                                                   const float* __restrict__ ndst,
                                                   const float* __restrict__ nsrc,
                                                   const float* __restrict__ b,
                                                   float* __restrict__ outT,
                                                   int N, int nstride, int scale_out) {
    int lane = threadIdx.x & 63;
    int warp = threadIdx.x >> 6;
    int c = blockIdx.x & 7;
    int esub = lane >> 3;
    int f = lane & 7;
    const float* __restrict__ chunk = tmpT + (size_t)c * N * CF;
    float bias = b[c * CF + f];

    int n = (blockIdx.x >> 3) * 4 + warp;
    if (n >= N) return;
    int beg = row_ptr[n];
    int end = row_ptr[n + 1];
    int myc = (beg + lane < end) ? col[beg + lane] : 0;

    while (true) {
        // prefetch next node's metadata + col chunk (independent of current work)
        int nn = n + nstride;
        int nbeg = 0, nend = 0, nmyc = 0;
        if (nn < N) {
            nbeg = row_ptr[nn];
            nend = row_ptr[nn + 1];
            nmyc = (nbeg + lane < nend) ? col[nbeg + lane] : 0;
        }

        int m = end - beg;
        float acc = 0.0f;
        if (m <= 64) {
#pragma unroll
            for (int t = 0; t < 8; t++) {
                int s = __shfl(myc, t * 8 + esub, 64);
                if (t * 8 + esub < m) acc += chunk[(size_t)s * CF + f];
            }
        } else {
            // rare fallback for degree > 64
            for (int base = beg; base < end; base += 8) {
                int j = base + esub;
                if (j < end) acc += chunk[(size_t)col[j] * CF + f];
            }
        }
        acc += __shfl_xor(acc, 8, 64);
        acc += __shfl_xor(acc, 16, 64);
        acc += __shfl_xor(acc, 32, 64);
        float o = acc * ndst[n] + bias;
        if (scale_out) o *= nsrc[n];
        if (lane < 8) outT[((size_t)c * N + n) * CF + lane] = o;

        if (nn >= N) break;
        n = nn; beg = nbeg; end = nend; myc = nmyc;
    }
}

// ---------- sum pooling from chunked layout ----------
__global__ __launch_bounds__(256) void pool_kernel(const int* __restrict__ gids,
                                                   const float* __restrict__ hT,
                                                   float* __restrict__ pooled, int N) {
    int lane = threadIdx.x & 63;
    int n = blockIdx.x * 4 + (threadIdx.x >> 6);
    if (n < N) {
        int g = gids[n];
        float v = hT[((size_t)(lane >> 3) * N + n) * CF + (lane & 7)];
        atomicAdd(&pooled[(size_t)g * HIDDEN + lane], v);
    }
}

// ---------- regression head ----------
__global__ __launch_bounds__(256) void head_kernel(const float* __restrict__ pooled,
                                                   const float* __restrict__ Wreg,
                                                   float* __restrict__ out, int G) {
    int lane = threadIdx.x & 63;
    int g = blockIdx.x * (blockDim.x >> 6) + (threadIdx.x >> 6);
    if (g < G) {
        float v = pooled[(size_t)g * HIDDEN + lane] * Wreg[lane];
#pragma unroll
        for (int off = 32; off > 0; off >>= 1) v += __shfl_down(v, off, 64);
        if (lane == 0) out[g] = v;
    }
}

extern "C" void kernel_launch(void* const* d_in, const int* in_sizes, int n_in,
                              void* d_out, int out_size, void* d_ws, size_t ws_size,
                              hipStream_t stream) {
    const int*   feats = (const int*)d_in[0];
    const int*   src   = (const int*)d_in[1];
    const int*   dst   = (const int*)d_in[2];
    const int*   gids  = (const int*)d_in[3];
    const float* emb   = (const float*)d_in[5];
    const float* Ws    = (const float*)d_in[6];
    const float* bs    = (const float*)d_in[7];
    const float* Wreg  = (const float*)d_in[8];
    float* out = (float*)d_out;

    int N = in_sizes[0];
    int E = in_sizes[1];
    const int G = 512;
    int NB = (N + 255) / 256;

    char* p = (char*)d_ws;
    float* nsrc    = (float*)p;  p += (size_t)N * 4;   // zeroed
    int*   indeg   = (int*)p;    p += (size_t)N * 4;   // zeroed
    float* ndst    = (float*)p;  p += (size_t)N * 4;
    int*   cursor  = (int*)p;    p += (size_t)N * 4;
    int*   row_ptr = (int*)p;    p += (size_t)(N + 1) * 4;
    int*   bsum    = (int*)p;    p += 1024 * 4;
    int*   col     = (int*)p;    p += (size_t)E * 4;
    p = (char*)(((uintptr_t)p + 255) & ~(uintptr_t)255);
    float* hbuf    = (float*)p;  p += (size_t)N * HIDDEN * 4;   // chunked layout
    float* tmp     = (float*)p;  p += (size_t)N * HIDDEN * 4;   // chunked layout
    float* pooled  = (float*)p;  p += (size_t)G * HIDDEN * 4;

    hipMemsetAsync(nsrc, 0, (size_t)N * 8, stream);
    hipMemsetAsync(pooled, 0, (size_t)G * HIDDEN * 4, stream);

    degree_kernel<<<(E + 255) / 256, 256, 0, stream>>>(src, dst, nsrc, indeg, E);
    norm_kernel<<<NB, 256, 0, stream>>>(nsrc, indeg, ndst, N);

    block_sum_kernel<<<NB, 256, 0, stream>>>(indeg, bsum, N);
    scan_bsum_kernel<<<1, 1024, 0, stream>>>(bsum, NB);
    scan_final_kernel<<<NB, 256, 0, stream>>>(indeg, bsum, cursor, row_ptr, N);
    fill_csr_kernel<<<(E + 255) / 256, 256, 0, stream>>>(src, dst, cursor, col, E);

    int total = N * HIDDEN;
    embed_kernel<<<(total + 255) / 256, 256, 0, stream>>>(feats, emb, nsrc, hbuf, N, total);

    const int GB_DENSE = 2048;
    const int GB_SPMM  = 1024;                 // per-chunk block groups (more iters/wave)
    int dstride = GB_DENSE * 4;
    int sstride = GB_SPMM * 4;

    for (int l = 0; l < 3; l++) {
        dense_kernel<<<GB_DENSE, 256, 0, stream>>>(hbuf, Ws + l * HIDDEN * HIDDEN,
                                                   tmp, N, dstride);
        spmm_kernel<<<NCHUNK * GB_SPMM, 256, 0, stream>>>(row_ptr, col, tmp, ndst, nsrc,
                                                          bs + l * HIDDEN, hbuf,
                                                          N, sstride, (l < 2) ? 1 : 0);
    }

    pool_kernel<<<(N + 3) / 4, 256, 0, stream>>>(gids, hbuf, pooled, N);
    head_kernel<<<(G + 3) / 4, 256, 0, stream>>>(pooled, Wreg, out, G);
}

// Round 5
// 837.566 us; speedup vs baseline: 1.4640x; 1.3908x over previous
//
#include <hip/hip_runtime.h>

#define HIDDEN 64
#define CF 8        // features per chunk
#define NCHUNK 8    // chunks (= XCD count)

// ---------- degree counting ----------
__global__ void degree_kernel(const int* __restrict__ src, const int* __restrict__ dst,
                              float* __restrict__ outdeg, int* __restrict__ indeg, int E) {
    int e = blockIdx.x * blockDim.x + threadIdx.x;
    if (e < E) {
        atomicAdd(&outdeg[src[e]], 1.0f);
        atomicAdd(&indeg[dst[e]], 1);
    }
}

__global__ void norm_kernel(float* __restrict__ nsrc, const int* __restrict__ indeg,
                            float* __restrict__ ndst, int N) {
    int i = blockIdx.x * blockDim.x + threadIdx.x;
    if (i < N) {
        nsrc[i] = rsqrtf(fmaxf(nsrc[i], 1.0f));
        ndst[i] = rsqrtf(fmaxf((float)indeg[i], 1.0f));
    }
}

// ---------- CSR build: scan over in-degrees ----------
__global__ void block_sum_kernel(const int* __restrict__ indeg, int* __restrict__ bsum, int N) {
    int t = threadIdx.x;
    int n = blockIdx.x * 256 + t;
    int v = (n < N) ? indeg[n] : 0;
#pragma unroll
    for (int off = 32; off > 0; off >>= 1) v += __shfl_down(v, off, 64);
    __shared__ int s[4];
    if ((t & 63) == 0) s[t >> 6] = v;
    __syncthreads();
    if (t == 0) bsum[blockIdx.x] = s[0] + s[1] + s[2] + s[3];
}

__global__ void scan_bsum_kernel(int* __restrict__ bsum, int B) {
    __shared__ int tmp[1024];
    int t = threadIdx.x;
    tmp[t] = (t < B) ? bsum[t] : 0;
    __syncthreads();
    for (int off = 1; off < 1024; off <<= 1) {
        int u = (t >= off) ? tmp[t - off] : 0;
        __syncthreads();
        tmp[t] += u;
        __syncthreads();
    }
    if (t < B) bsum[t] = (t > 0) ? tmp[t - 1] : 0;
}

__global__ void scan_final_kernel(const int* __restrict__ indeg, const int* __restrict__ bsum,
                                  int* __restrict__ cursor, int* __restrict__ row_ptr, int N) {
    __shared__ int tmp[256];
    int t = threadIdx.x;
    int n = blockIdx.x * 256 + t;
    int v = (n < N) ? indeg[n] : 0;
    tmp[t] = v;
    __syncthreads();
    for (int off = 1; off < 256; off <<= 1) {
        int u = (t >= off) ? tmp[t - off] : 0;
        __syncthreads();
        tmp[t] += u;
        __syncthreads();
    }
    if (n < N) {
        int incl = tmp[t] + bsum[blockIdx.x];
        row_ptr[n + 1] = incl;
        cursor[n] = incl - v;
    }
    if (n == 0) row_ptr[0] = 0;
}

__global__ void fill_csr_kernel(const int* __restrict__ src, const int* __restrict__ dst,
                                int* __restrict__ cursor, int* __restrict__ col, int E) {
    int e = blockIdx.x * blockDim.x + threadIdx.x;
    if (e < E) {
        int d = dst[e];
        int slot = atomicAdd(&cursor[d], 1);
        col[slot] = src[e];
    }
}

// ---------- embW = emb @ W0  (row-major [VOCAB][64]) ----------
__global__ __launch_bounds__(256) void embw_kernel(const float* __restrict__ emb,
                                                   const float* __restrict__ W,
                                                   float* __restrict__ embW, int V) {
    __shared__ float Wsh[HIDDEN * HIDDEN];
    for (int i = threadIdx.x; i < HIDDEN * HIDDEN; i += blockDim.x) Wsh[i] = W[i];
    __syncthreads();
    int lane = threadIdx.x & 63;
    int v = blockIdx.x * 4 + (threadIdx.x >> 6);
    if (v >= V) return;
    float rv = emb[(size_t)v * HIDDEN + lane];
    float o = 0.0f;
#pragma unroll
    for (int k = 0; k < HIDDEN; k++) o = fmaf(__shfl(rv, k, 64), Wsh[k * HIDDEN + lane], o);
    embW[(size_t)v * HIDDEN + lane] = o;
}

// ---------- w~ = W2 @ Wreg (64) + c3 = b2 . Wreg (stored at wt[64]) ----------
__global__ void wtilde_kernel(const float* __restrict__ W2, const float* __restrict__ Wreg,
                              const float* __restrict__ b2, float* __restrict__ wt) {
    int k = threadIdx.x;   // 0..63
    float s = 0.0f;
    for (int j = 0; j < HIDDEN; j++) s += W2[k * HIDDEN + j] * Wreg[j];
    wt[k] = s;
    float cv = b2[k] * Wreg[k];
#pragma unroll
    for (int off = 32; off > 0; off >>= 1) cv += __shfl_down(cv, off, 64);
    if (k == 0) wt[HIDDEN] = cv;
}

// ---------- gather1: tmp[c][n][f] = embW[feats[n]][c*8+f] * nsrc[n] ----------
__global__ void gather1_kernel(const int* __restrict__ feats, const float* __restrict__ embW,
                               const float* __restrict__ nsrc, float* __restrict__ hT,
                               int N, int total) {
    int idx = blockIdx.x * blockDim.x + threadIdx.x;
    if (idx >= total) return;
    int c = idx / (N * CF);
    int r = idx - c * (N * CF);
    int n = r >> 3;
    int f = r & 7;
    hT[idx] = embW[feats[n] * HIDDEN + c * CF + f] * nsrc[n];
}

// ---------- dense 64x64 layer, chunked in/out: outT = inT @ W ----------
__global__ __launch_bounds__(256) void dense_kernel(const float* __restrict__ inT,
                                                    const float* __restrict__ W,
                                                    float* __restrict__ outT,
                                                    int N, int nstride) {
    __shared__ float Wsh[HIDDEN * HIDDEN];
    for (int i = threadIdx.x; i < HIDDEN * HIDDEN; i += blockDim.x) Wsh[i] = W[i];
    __syncthreads();

    int lane = threadIdx.x & 63;
    int warp = threadIdx.x >> 6;
    int c = lane >> 3, f = lane & 7;

    for (int n = blockIdx.x * 4 + warp; n < N; n += nstride) {
        float rv = inT[((size_t)c * N + n) * CF + f];
        float o = 0.0f;
#pragma unroll
        for (int k = 0; k < HIDDEN; k++) {
            o = fmaf(__shfl(rv, k, 64), Wsh[k * HIDDEN + lane], o);
        }
        outT[((size_t)c * N + n) * CF + f] = o;
    }
}

// ---------- slim chunked gather-SpMM ----------
// chunk c = blockIdx & 7 (XCD-pinned). lane = f*8 + esub: f = lane>>3 (feature),
// esub = lane&7 (edge slot). Dynamic loop, 2-way unrolled, per-lane col loads
// (no bpermute), clamped-index loads + select (no exec-mask dance).
// out = ((sum_s in[s]) * ndst + b) * nsrc   (chunked layout)
__global__ __launch_bounds__(256) void spmm_kernel(const int* __restrict__ row_ptr,
                                                   const int* __restrict__ col,
                                                   const float* __restrict__ tmpT,
                                                   const float* __restrict__ ndst,
                                                   const float* __restrict__ nsrc,
                                                   const float* __restrict__ b,
                                                   float* __restrict__ outT,
                                                   int N, int nstride) {
    int lane = threadIdx.x & 63;
    int warp = threadIdx.x >> 6;
    int c = blockIdx.x & 7;
    int f = lane >> 3;
    int esub = lane & 7;
    const float* __restrict__ chunk = tmpT + (size_t)c * N * CF;
    float bias = b[c * CF + f];

    for (int n = (blockIdx.x >> 3) * 4 + warp; n < N; n += nstride) {
        int beg = row_ptr[n];
        int end = row_ptr[n + 1];
        float acc0 = 0.0f, acc1 = 0.0f;
        for (int j = beg; j < end; j += 16) {
            int i0 = j + esub;
            int i1 = i0 + 8;
            int s0 = col[min(i0, end - 1)];
            int s1 = col[min(i1, end - 1)];
            float v0 = chunk[(size_t)s0 * CF + f];
            float v1 = chunk[(size_t)s1 * CF + f];
            acc0 += (i0 < end) ? v0 : 0.0f;
            acc1 += (i1 < end) ? v1 : 0.0f;
        }
        float acc = acc0 + acc1;
        acc += __shfl_xor(acc, 1, 64);
        acc += __shfl_xor(acc, 2, 64);
        acc += __shfl_xor(acc, 4, 64);
        float o = (acc * ndst[n] + bias) * nsrc[n];
        if (esub == 0) outT[((size_t)c * N + n) * CF + f] = o;
    }
}

// ---------- q[n] = hT[n] . w~  (full 64-dot from chunked layout) ----------
__global__ __launch_bounds__(256) void qdot_kernel(const float* __restrict__ hT,
                                                   const float* __restrict__ wt,
                                                   float* __restrict__ q, int N) {
    int lane = threadIdx.x & 63;
    int ns = lane >> 3, f = lane & 7;
    int n = (blockIdx.x * 4 + (threadIdx.x >> 6)) * 8 + ns;
    float acc = 0.0f;
#pragma unroll
    for (int c = 0; c < NCHUNK; c++) {
        float v = (n < N) ? hT[((size_t)c * N + n) * CF + f] : 0.0f;
        acc += v * wt[c * CF + f];
    }
    acc += __shfl_xor(acc, 1, 64);
    acc += __shfl_xor(acc, 2, 64);
    acc += __shfl_xor(acc, 4, 64);
    if (f == 0 && n < N) q[n] = acc;
}

// ---------- layer-3 scalar gather: nodeval[n] = (sum_s q[s]) * ndst[n] ----------
__global__ __launch_bounds__(256) void spmm3_kernel(const int* __restrict__ row_ptr,
                                                    const int* __restrict__ col,
                                                    const float* __restrict__ q,
                                                    const float* __restrict__ ndst,
                                                    float* __restrict__ nodeval, int N) {
    int lane = threadIdx.x & 63;
    int n = blockIdx.x * 4 + (threadIdx.x >> 6);
    if (n >= N) return;
    int beg = row_ptr[n];
    int end = row_ptr[n + 1];
    float acc = 0.0f;
    for (int j = beg; j < end; j += 64) {
        int idx = j + lane;
        float v = q[col[min(idx, end - 1)]];
        acc += (idx < end) ? v : 0.0f;
    }
#pragma unroll
    for (int off = 1; off < 64; off <<= 1) acc += __shfl_xor(acc, off, 64);
    if (lane == 0) nodeval[n] = acc * ndst[n];
}

// ---------- final: out[g] += segmented sum of (nodeval[n] + c3) over sorted gids ----------
__global__ __launch_bounds__(256) void final_kernel(const int* __restrict__ gids,
                                                    const float* __restrict__ nodeval,
                                                    const float* __restrict__ wt,
                                                    float* __restrict__ out, int N) {
    int n = blockIdx.x * 256 + threadIdx.x;
    int lane = threadIdx.x & 63;
    float c3 = wt[HIDDEN];
    float v = 0.0f;
    int g = -1;
    if (n < N) { v = nodeval[n] + c3; g = gids[n]; }
#pragma unroll
    for (int off = 1; off < 64; off <<= 1) {
        float u = __shfl_up(v, off, 64);
        int gu = __shfl_up(g, off, 64);
        if (lane >= off && gu == g) v += u;
    }
    int gn = __shfl_down(g, 1, 64);
    bool last = (lane == 63) || (gn != g);
    if (n < N && last) atomicAdd(&out[g], v);
}

extern "C" void kernel_launch(void* const* d_in, const int* in_sizes, int n_in,
                              void* d_out, int out_size, void* d_ws, size_t ws_size,
                              hipStream_t stream) {
    const int*   feats = (const int*)d_in[0];
    const int*   src   = (const int*)d_in[1];
    const int*   dst   = (const int*)d_in[2];
    const int*   gids  = (const int*)d_in[3];
    const float* emb   = (const float*)d_in[5];
    const float* Ws    = (const float*)d_in[6];
    const float* bs    = (const float*)d_in[7];
    const float* Wreg  = (const float*)d_in[8];
    float* out = (float*)d_out;

    int N = in_sizes[0];
    int E = in_sizes[1];
    int V = in_sizes[5] / HIDDEN;   // vocab
    int NB = (N + 255) / 256;

    char* p = (char*)d_ws;
    float* nsrc    = (float*)p;  p += (size_t)N * 4;   // zeroed
    int*   indeg   = (int*)p;    p += (size_t)N * 4;   // zeroed
    float* ndst    = (float*)p;  p += (size_t)N * 4;
    int*   cursor  = (int*)p;    p += (size_t)N * 4;
    int*   row_ptr = (int*)p;    p += (size_t)(N + 1) * 4;
    int*   bsum    = (int*)p;    p += 1024 * 4;
    float* wt      = (float*)p;  p += (HIDDEN + 1) * 4;
    float* q       = (float*)p;  p += (size_t)N * 4;
    float* nodeval = (float*)p;  p += (size_t)N * 4;
    int*   col     = (int*)p;    p += (size_t)E * 4;
    p = (char*)(((uintptr_t)p + 255) & ~(uintptr_t)255);
    float* embW    = (float*)p;  p += (size_t)V * HIDDEN * 4;
    float* hbuf    = (float*)p;  p += (size_t)N * HIDDEN * 4;   // chunked layout
    float* tmp     = (float*)p;  p += (size_t)N * HIDDEN * 4;   // chunked layout

    hipMemsetAsync(nsrc, 0, (size_t)N * 8, stream);          // nsrc + indeg
    hipMemsetAsync(out, 0, (size_t)out_size * 4, stream);

    degree_kernel<<<(E + 255) / 256, 256, 0, stream>>>(src, dst, nsrc, indeg, E);
    norm_kernel<<<NB, 256, 0, stream>>>(nsrc, indeg, ndst, N);

    block_sum_kernel<<<NB, 256, 0, stream>>>(indeg, bsum, N);
    scan_bsum_kernel<<<1, 1024, 0, stream>>>(bsum, NB);
    scan_final_kernel<<<NB, 256, 0, stream>>>(indeg, bsum, cursor, row_ptr, N);
    fill_csr_kernel<<<(E + 255) / 256, 256, 0, stream>>>(src, dst, cursor, col, E);

    embw_kernel<<<(V + 3) / 4, 256, 0, stream>>>(emb, Ws + 0 * HIDDEN * HIDDEN, embW, V);
    wtilde_kernel<<<1, 64, 0, stream>>>(Ws + 2 * HIDDEN * HIDDEN, Wreg, bs + 2 * HIDDEN, wt);

    int total = N * HIDDEN;
    gather1_kernel<<<(total + 255) / 256, 256, 0, stream>>>(feats, embW, nsrc, tmp, N, total);

    const int GB_DENSE = 2048;
    const int GB_SPMM  = 1024;
    int dstride = GB_DENSE * 4;
    int sstride = GB_SPMM * 4;

    // layer 1: hbuf = ((A tmp)*ndst + b0)*nsrc
    spmm_kernel<<<NCHUNK * GB_SPMM, 256, 0, stream>>>(row_ptr, col, tmp, ndst, nsrc,
                                                      bs + 0 * HIDDEN, hbuf, N, sstride);
    // layer 2: tmp = hbuf @ W1 ; hbuf = ((A tmp)*ndst + b1)*nsrc
    dense_kernel<<<GB_DENSE, 256, 0, stream>>>(hbuf, Ws + 1 * HIDDEN * HIDDEN, tmp, N, dstride);
    spmm_kernel<<<NCHUNK * GB_SPMM, 256, 0, stream>>>(row_ptr, col, tmp, ndst, nsrc,
                                                      bs + 1 * HIDDEN, hbuf, N, sstride);
    // layer 3 collapsed: q = hbuf . w~ ; nodeval = (A q)*ndst ; out = seg-sum(nodeval + c3)
    qdot_kernel<<<(N + 31) / 32, 256, 0, stream>>>(hbuf, wt, q, N);
    spmm3_kernel<<<(N + 3) / 4, 256, 0, stream>>>(row_ptr, col, q, ndst, nodeval, N);
    final_kernel<<<NB, 256, 0, stream>>>(gids, nodeval, wt, out, N);
}

// Round 6
// 654.657 us; speedup vs baseline: 1.8730x; 1.2794x over previous
//
#include <hip/hip_runtime.h>

#define HIDDEN 64
#define CF 16       // features per chunk
#define NCHUNK 4    // chunks; chunk = blockIdx&3, XCD-spread

// ---------- degree counting ----------
__global__ void degree_kernel(const int* __restrict__ src, const int* __restrict__ dst,
                              float* __restrict__ outdeg, int* __restrict__ indeg, int E) {
    int e = blockIdx.x * blockDim.x + threadIdx.x;
    if (e < E) {
        atomicAdd(&outdeg[src[e]], 1.0f);
        atomicAdd(&indeg[dst[e]], 1);
    }
}

// ---------- fused: norms + padded-degree block sums ----------
__global__ void norm_bsum_kernel(float* __restrict__ nsrc, const int* __restrict__ indeg,
                                 float* __restrict__ ndst, int* __restrict__ bsum, int N) {
    int t = threadIdx.x;
    int n = blockIdx.x * 256 + t;
    int deg = (n < N) ? indeg[n] : 0;
    if (n < N) {
        nsrc[n] = rsqrtf(fmaxf(nsrc[n], 1.0f));
        ndst[n] = rsqrtf(fmaxf((float)deg, 1.0f));
    }
    int v = (deg + 15) & ~15;   // padded degree
#pragma unroll
    for (int off = 32; off > 0; off >>= 1) v += __shfl_down(v, off, 64);
    __shared__ int s[4];
    if ((t & 63) == 0) s[t >> 6] = v;
    __syncthreads();
    if (t == 0) bsum[blockIdx.x] = s[0] + s[1] + s[2] + s[3];
}

__global__ void scan_bsum_kernel(int* __restrict__ bsum, int B) {
    __shared__ int tmp[1024];
    int t = threadIdx.x;
    tmp[t] = (t < B) ? bsum[t] : 0;
    __syncthreads();
    for (int off = 1; off < 1024; off <<= 1) {
        int u = (t >= off) ? tmp[t - off] : 0;
        __syncthreads();
        tmp[t] += u;
        __syncthreads();
    }
    if (t < B) bsum[t] = (t > 0) ? tmp[t - 1] : 0;
}

// padded inclusive scan -> row_ptr (padded CSR); cursor = padded row start
__global__ void scan_final_kernel(const int* __restrict__ indeg, const int* __restrict__ bsum,
                                  int* __restrict__ cursor, int* __restrict__ row_ptr, int N) {
    __shared__ int tmp[256];
    int t = threadIdx.x;
    int n = blockIdx.x * 256 + t;
    int v = (n < N) ? ((indeg[n] + 15) & ~15) : 0;
    tmp[t] = v;
    __syncthreads();
    for (int off = 1; off < 256; off <<= 1) {
        int u = (t >= off) ? tmp[t - off] : 0;
        __syncthreads();
        tmp[t] += u;
        __syncthreads();
    }
    if (n < N) {
        int incl = tmp[t] + bsum[blockIdx.x];
        row_ptr[n + 1] = incl;
        cursor[n] = incl - v;
    }
    if (n == 0) row_ptr[0] = 0;
}

// pre-fill col with sentinel N (pad slots keep it; real edges overwrite)
__global__ void fill_col_kernel(int* __restrict__ col, int val, int Ecap) {
    int i = blockIdx.x * 256 + threadIdx.x;
    if (i < Ecap) col[i] = val;
}

__global__ void fill_csr_kernel(const int* __restrict__ src, const int* __restrict__ dst,
                                int* __restrict__ cursor, int* __restrict__ col, int E) {
    int e = blockIdx.x * blockDim.x + threadIdx.x;
    if (e < E) {
        int d = dst[e];
        int slot = atomicAdd(&cursor[d], 1);
        col[slot] = src[e];
    }
}

// zero the sentinel rows (node N) of tmp chunks + q[N]
__global__ void zsent_kernel(float* __restrict__ tmp, float* __restrict__ q, int N, int N1) {
    int l = threadIdx.x;   // 64
    int c = l >> 4, f = l & 15;
    tmp[((size_t)c * N1 + N) * CF + f] = 0.0f;
    if (l == 0) q[N] = 0.0f;
}

// ---------- embW = emb @ W0 ----------
__global__ __launch_bounds__(256) void embw_kernel(const float* __restrict__ emb,
                                                   const float* __restrict__ W,
                                                   float* __restrict__ embW, int V) {
    __shared__ float Wsh[HIDDEN * HIDDEN];
    for (int i = threadIdx.x; i < HIDDEN * HIDDEN; i += blockDim.x) Wsh[i] = W[i];
    __syncthreads();
    int lane = threadIdx.x & 63;
    int v = blockIdx.x * 4 + (threadIdx.x >> 6);
    if (v >= V) return;
    float rv = emb[(size_t)v * HIDDEN + lane];
    float o = 0.0f;
#pragma unroll
    for (int k = 0; k < HIDDEN; k++) o = fmaf(__shfl(rv, k, 64), Wsh[k * HIDDEN + lane], o);
    embW[(size_t)v * HIDDEN + lane] = o;
}

// ---------- w~ = W2 @ Wreg ; wt[64] = b2 . Wreg ----------
__global__ void wtilde_kernel(const float* __restrict__ W2, const float* __restrict__ Wreg,
                              const float* __restrict__ b2, float* __restrict__ wt) {
    int k = threadIdx.x;
    float s = 0.0f;
    for (int j = 0; j < HIDDEN; j++) s += W2[k * HIDDEN + j] * Wreg[j];
    wt[k] = s;
    float cv = b2[k] * Wreg[k];
#pragma unroll
    for (int off = 32; off > 0; off >>= 1) cv += __shfl_down(cv, off, 64);
    if (k == 0) wt[HIDDEN] = cv;
}

// ---------- gather1: tmp[c][n][f] = embW[feats[n]][c*16+f] * nsrc[n] ----------
__global__ void gather1_kernel(const int* __restrict__ feats, const float* __restrict__ embW,
                               const float* __restrict__ nsrc, float* __restrict__ hT,
                               int N, int N1, int total) {
    int idx = blockIdx.x * blockDim.x + threadIdx.x;
    if (idx >= total) return;
    int c = idx / (N * CF);
    int r = idx - c * (N * CF);
    int n = r >> 4;
    int f = r & 15;
    hT[((size_t)c * N1 + n) * CF + f] = embW[feats[n] * HIDDEN + c * CF + f] * nsrc[n];
}

// ---------- dense 64x64 layer, chunked CF16 in/out: outT = inT @ W ----------
__global__ __launch_bounds__(256) void dense_kernel(const float* __restrict__ inT,
                                                    const float* __restrict__ W,
                                                    float* __restrict__ outT,
                                                    int N, int N1, int nstride) {
    __shared__ float Wsh[HIDDEN * HIDDEN];
    for (int i = threadIdx.x; i < HIDDEN * HIDDEN; i += blockDim.x) Wsh[i] = W[i];
    __syncthreads();

    int lane = threadIdx.x & 63;
    int warp = threadIdx.x >> 6;
    size_t rowoff = (size_t)(lane >> 4) * N1;   // chunk base row
    int f = lane & 15;

    for (int n = blockIdx.x * 4 + warp; n < N; n += nstride) {
        float rv = inT[(rowoff + n) * CF + f];   // = in[n][lane]
        float o = 0.0f;
#pragma unroll
        for (int k = 0; k < HIDDEN; k++) {
            o = fmaf(__shfl(rv, k, 64), Wsh[k * HIDDEN + lane], o);
        }
        outT[(rowoff + n) * CF + f] = o;
    }
}

// ---------- chunked gather-SpMM: padded CSR, float4, 2-node interleave ----------
// lane = e*4 + fq: e = lane>>2 (16 edge slots), fq = lane&3 (float4 group).
// out = ((A in)*ndst + b)*nsrc  in CF16 chunked layout.
__global__ __launch_bounds__(256) void spmm_kernel(const int* __restrict__ row_ptr,
                                                   const int* __restrict__ col,
                                                   const float* __restrict__ tmpT,
                                                   const float* __restrict__ ndst,
                                                   const float* __restrict__ nsrc,
                                                   const float* __restrict__ b,
                                                   float* __restrict__ outT,
                                                   int N, int N1, int nstride) {
    int lane = threadIdx.x & 63;
    int warp = threadIdx.x >> 6;
    int c = blockIdx.x & 3;
    int e = lane >> 2;
    int fq = lane & 3;
    const float* __restrict__ chunk = tmpT + (size_t)c * N1 * CF;
    float4 bias = ((const float4*)(b + c * CF))[fq];

    int start = (blockIdx.x >> 2) * 4 + warp;
    for (int n0 = start; n0 < N; n0 += 2 * nstride) {
        int n1 = n0 + nstride;
        int beg0 = row_ptr[n0], end0 = row_ptr[n0 + 1];
        int beg1 = 0, end1 = 0;
        if (n1 < N) { beg1 = row_ptr[n1]; end1 = row_ptr[n1 + 1]; }
        float4 acc0 = make_float4(0.f, 0.f, 0.f, 0.f);
        float4 acc1 = make_float4(0.f, 0.f, 0.f, 0.f);
        int j0 = beg0 + e, j1 = beg1 + e;
        // interleaved: 4 independent loads in flight (wave-uniform conditions)
        while (j0 < end0 && j1 < end1) {
            int s0 = col[j0], s1 = col[j1];
            float4 v0 = *(const float4*)(chunk + (size_t)s0 * CF + fq * 4);
            float4 v1 = *(const float4*)(chunk + (size_t)s1 * CF + fq * 4);
            acc0.x += v0.x; acc0.y += v0.y; acc0.z += v0.z; acc0.w += v0.w;
            acc1.x += v1.x; acc1.y += v1.y; acc1.z += v1.z; acc1.w += v1.w;
            j0 += 16; j1 += 16;
        }
        while (j0 < end0) {
            int s0 = col[j0];
            float4 v0 = *(const float4*)(chunk + (size_t)s0 * CF + fq * 4);
            acc0.x += v0.x; acc0.y += v0.y; acc0.z += v0.z; acc0.w += v0.w;
            j0 += 16;
        }
        while (j1 < end1) {
            int s1 = col[j1];
            float4 v1 = *(const float4*)(chunk + (size_t)s1 * CF + fq * 4);
            acc1.x += v1.x; acc1.y += v1.y; acc1.z += v1.z; acc1.w += v1.w;
            j1 += 16;
        }
#pragma unroll
        for (int m = 4; m < 64; m <<= 1) {
            acc0.x += __shfl_xor(acc0.x, m, 64); acc0.y += __shfl_xor(acc0.y, m, 64);
            acc0.z += __shfl_xor(acc0.z, m, 64); acc0.w += __shfl_xor(acc0.w, m, 64);
            acc1.x += __shfl_xor(acc1.x, m, 64); acc1.y += __shfl_xor(acc1.y, m, 64);
            acc1.z += __shfl_xor(acc1.z, m, 64); acc1.w += __shfl_xor(acc1.w, m, 64);
        }
        if (e == 0) {
            float nd = ndst[n0], ns = nsrc[n0];
            float4 o;
            o.x = (acc0.x * nd + bias.x) * ns;
            o.y = (acc0.y * nd + bias.y) * ns;
            o.z = (acc0.z * nd + bias.z) * ns;
            o.w = (acc0.w * nd + bias.w) * ns;
            *(float4*)(outT + ((size_t)c * N1 + n0) * CF + fq * 4) = o;
            if (n1 < N) {
                nd = ndst[n1]; ns = nsrc[n1];
                o.x = (acc1.x * nd + bias.x) * ns;
                o.y = (acc1.y * nd + bias.y) * ns;
                o.z = (acc1.z * nd + bias.z) * ns;
                o.w = (acc1.w * nd + bias.w) * ns;
                *(float4*)(outT + ((size_t)c * N1 + n1) * CF + fq * 4) = o;
            }
        }
    }
}

// ---------- q[n] = hT[n] . w~ ----------
__global__ __launch_bounds__(256) void qdot_kernel(const float* __restrict__ hT,
                                                   const float* __restrict__ wt,
                                                   float* __restrict__ q, int N, int N1) {
    int lane = threadIdx.x & 63;
    int warp = threadIdx.x >> 6;
    int ns_ = lane >> 4, f = lane & 15;
    int n = (blockIdx.x * 4 + warp) * 4 + ns_;
    float acc = 0.0f;
#pragma unroll
    for (int c = 0; c < NCHUNK; c++) {
        float v = (n < N) ? hT[((size_t)c * N1 + n) * CF + f] : 0.0f;
        acc += v * wt[c * CF + f];
    }
    acc += __shfl_xor(acc, 1, 64);
    acc += __shfl_xor(acc, 2, 64);
    acc += __shfl_xor(acc, 4, 64);
    acc += __shfl_xor(acc, 8, 64);
    if (f == 0 && n < N) q[n] = acc;
}

// ---------- layer-3 scalar gather (padded CSR, 16 lanes/node) ----------
__global__ __launch_bounds__(256) void spmm3_kernel(const int* __restrict__ row_ptr,
                                                    const int* __restrict__ col,
                                                    const float* __restrict__ q,
                                                    const float* __restrict__ ndst,
                                                    float* __restrict__ nodeval, int N) {
    int lane = threadIdx.x & 63;
    int warp = threadIdx.x >> 6;
    int ns_ = lane >> 4, ln = lane & 15;
    int n = blockIdx.x * 16 + warp * 4 + ns_;
    if (n >= N) return;
    int beg = row_ptr[n], end = row_ptr[n + 1];
    float acc = 0.0f;
    for (int j = beg + ln; j < end; j += 16) acc += q[col[j]];
    acc += __shfl_xor(acc, 1, 64);
    acc += __shfl_xor(acc, 2, 64);
    acc += __shfl_xor(acc, 4, 64);
    acc += __shfl_xor(acc, 8, 64);
    if (ln == 0) nodeval[n] = acc * ndst[n];
}

// ---------- final: segmented sum over sorted gids ----------
__global__ __launch_bounds__(256) void final_kernel(const int* __restrict__ gids,
                                                    const float* __restrict__ nodeval,
                                                    const float* __restrict__ wt,
                                                    float* __restrict__ out, int N) {
    int n = blockIdx.x * 256 + threadIdx.x;
    int lane = threadIdx.x & 63;
    float c3 = wt[HIDDEN];
    float v = 0.0f;
    int g = -1;
    if (n < N) { v = nodeval[n] + c3; g = gids[n]; }
#pragma unroll
    for (int off = 1; off < 64; off <<= 1) {
        float u = __shfl_up(v, off, 64);
        int gu = __shfl_up(g, off, 64);
        if (lane >= off && gu == g) v += u;
    }
    int gn = __shfl_down(g, 1, 64);
    bool last = (lane == 63) || (gn != g);
    if (n < N && last) atomicAdd(&out[g], v);
}

extern "C" void kernel_launch(void* const* d_in, const int* in_sizes, int n_in,
                              void* d_out, int out_size, void* d_ws, size_t ws_size,
                              hipStream_t stream) {
    const int*   feats = (const int*)d_in[0];
    const int*   src   = (const int*)d_in[1];
    const int*   dst   = (const int*)d_in[2];
    const int*   gids  = (const int*)d_in[3];
    const float* emb   = (const float*)d_in[5];
    const float* Ws    = (const float*)d_in[6];
    const float* bs    = (const float*)d_in[7];
    const float* Wreg  = (const float*)d_in[8];
    float* out = (float*)d_out;

    int N = in_sizes[0];
    int E = in_sizes[1];
    int V = in_sizes[5] / HIDDEN;
    int N1 = N + 1;                 // +1 sentinel row per chunk
    int NB = (N + 255) / 256;
    int Ecap = E + 15 * N;          // upper bound on padded edge count

    char* p = (char*)d_ws;
    float* nsrc    = (float*)p;  p += (size_t)N * 4;   // zeroed
    int*   indeg   = (int*)p;    p += (size_t)N * 4;   // zeroed
    float* ndst    = (float*)p;  p += (size_t)N * 4;
    int*   cursor  = (int*)p;    p += (size_t)N * 4;
    int*   row_ptr = (int*)p;    p += (size_t)(N + 1) * 4;
    int*   bsum    = (int*)p;    p += 1024 * 4;
    float* wt      = (float*)p;  p += (HIDDEN + 1) * 4;
    float* q       = (float*)p;  p += (size_t)(N + 1) * 4;   // + sentinel
    float* nodeval = (float*)p;  p += (size_t)N * 4;
    int*   col     = (int*)p;    p += (size_t)Ecap * 4;
    p = (char*)(((uintptr_t)p + 255) & ~(uintptr_t)255);
    float* embW    = (float*)p;  p += (size_t)V * HIDDEN * 4;
    float* hbuf    = (float*)p;  p += (size_t)N1 * HIDDEN * 4;   // CF16 chunked
    float* tmp     = (float*)p;  p += (size_t)N1 * HIDDEN * 4;   // CF16 chunked

    hipMemsetAsync(nsrc, 0, (size_t)N * 8, stream);          // nsrc + indeg
    hipMemsetAsync(out, 0, (size_t)out_size * 4, stream);

    zsent_kernel<<<1, 64, 0, stream>>>(tmp, q, N, N1);
    degree_kernel<<<(E + 255) / 256, 256, 0, stream>>>(src, dst, nsrc, indeg, E);
    norm_bsum_kernel<<<NB, 256, 0, stream>>>(nsrc, indeg, ndst, bsum, N);
    scan_bsum_kernel<<<1, 1024, 0, stream>>>(bsum, NB);
    scan_final_kernel<<<NB, 256, 0, stream>>>(indeg, bsum, cursor, row_ptr, N);
    fill_col_kernel<<<(Ecap + 255) / 256, 256, 0, stream>>>(col, N, Ecap);
    fill_csr_kernel<<<(E + 255) / 256, 256, 0, stream>>>(src, dst, cursor, col, E);

    embw_kernel<<<(V + 3) / 4, 256, 0, stream>>>(emb, Ws + 0 * HIDDEN * HIDDEN, embW, V);
    wtilde_kernel<<<1, 64, 0, stream>>>(Ws + 2 * HIDDEN * HIDDEN, Wreg, bs + 2 * HIDDEN, wt);

    int total = N * HIDDEN;
    gather1_kernel<<<(total + 255) / 256, 256, 0, stream>>>(feats, embW, nsrc, tmp, N, N1, total);

    const int GB_SPMM = 1024;             // block groups per chunk
    const int GB_DENSE = 2048;
    int sstride = GB_SPMM * 4;
    int dstride = GB_DENSE * 4;

    // layer 1: hbuf = ((A tmp)*ndst + b0)*nsrc
    spmm_kernel<<<NCHUNK * GB_SPMM, 256, 0, stream>>>(row_ptr, col, tmp, ndst, nsrc,
                                                      bs + 0 * HIDDEN, hbuf, N, N1, sstride);
    // layer 2: tmp = hbuf @ W1 ; hbuf = ((A tmp)*ndst + b1)*nsrc
    dense_kernel<<<GB_DENSE, 256, 0, stream>>>(hbuf, Ws + 1 * HIDDEN * HIDDEN, tmp, N, N1, dstride);
    spmm_kernel<<<NCHUNK * GB_SPMM, 256, 0, stream>>>(row_ptr, col, tmp, ndst, nsrc,
                                                      bs + 1 * HIDDEN, hbuf, N, N1, sstride);
    // collapsed layer 3
    qdot_kernel<<<(N + 15) / 16, 256, 0, stream>>>(hbuf, wt, q, N, N1);
    spmm3_kernel<<<(N + 15) / 16, 256, 0, stream>>>(row_ptr, col, q, ndst, nodeval, N);
    final_kernel<<<NB, 256, 0, stream>>>(gids, nodeval, wt, out, N);
}

// Round 7
// 566.154 us; speedup vs baseline: 2.1658x; 1.1563x over previous
//
#include <hip/hip_runtime.h>

#define HIDDEN 64
#define CF 16       // features per chunk
#define NCHUNK 4    // chunks; chunk = blockIdx&3, XCD-spread

// ---------- merged rank pass: 2 atomic transactions per edge ----------
// cursor[d] counts up (ends = in-degree); rank[e] = within-row slot.
// outdeg[s] counts up (for nsrc).
__global__ void rank_kernel(const int* __restrict__ src, const int* __restrict__ dst,
                            int* __restrict__ outdeg, int* __restrict__ cursor,
                            int* __restrict__ rank, int E) {
    int e = blockIdx.x * blockDim.x + threadIdx.x;
    if (e < E) {
        rank[e] = atomicAdd(&cursor[dst[e]], 1);
        atomicAdd(&outdeg[src[e]], 1);
    }
}

// ---------- fused: norms + padded-degree block sums ----------
__global__ void norm_bsum_kernel(const int* __restrict__ outdeg, const int* __restrict__ indeg,
                                 float* __restrict__ nsrc, float* __restrict__ ndst,
                                 int* __restrict__ bsum, int N) {
    int t = threadIdx.x;
    int n = blockIdx.x * 256 + t;
    int deg = (n < N) ? indeg[n] : 0;
    if (n < N) {
        nsrc[n] = rsqrtf(fmaxf((float)outdeg[n], 1.0f));
        ndst[n] = rsqrtf(fmaxf((float)deg, 1.0f));
    }
    int v = (deg + 15) & ~15;   // padded degree
#pragma unroll
    for (int off = 32; off > 0; off >>= 1) v += __shfl_down(v, off, 64);
    __shared__ int s[4];
    if ((t & 63) == 0) s[t >> 6] = v;
    __syncthreads();
    if (t == 0) bsum[blockIdx.x] = s[0] + s[1] + s[2] + s[3];
}

__global__ void scan_bsum_kernel(int* __restrict__ bsum, int B) {
    __shared__ int tmp[1024];
    int t = threadIdx.x;
    tmp[t] = (t < B) ? bsum[t] : 0;
    __syncthreads();
    for (int off = 1; off < 1024; off <<= 1) {
        int u = (t >= off) ? tmp[t - off] : 0;
        __syncthreads();
        tmp[t] += u;
        __syncthreads();
    }
    if (t < B) bsum[t] = (t > 0) ? tmp[t - 1] : 0;
}

// padded inclusive scan -> row_ptr (padded CSR)
__global__ void scan_final_kernel(const int* __restrict__ indeg, const int* __restrict__ bsum,
                                  int* __restrict__ row_ptr, int N) {
    __shared__ int tmp[256];
    int t = threadIdx.x;
    int n = blockIdx.x * 256 + t;
    int v = (n < N) ? ((indeg[n] + 15) & ~15) : 0;
    tmp[t] = v;
    __syncthreads();
    for (int off = 1; off < 256; off <<= 1) {
        int u = (t >= off) ? tmp[t - off] : 0;
        __syncthreads();
        tmp[t] += u;
        __syncthreads();
    }
    if (n < N) row_ptr[n + 1] = tmp[t] + bsum[blockIdx.x];
    if (n == 0) row_ptr[0] = 0;
}

// pre-fill col with sentinel N (pad slots keep it; real edges overwrite)
__global__ void fill_col_kernel(int* __restrict__ col, int val, int Ecap) {
    int i = blockIdx.x * 256 + threadIdx.x;
    if (i < Ecap) col[i] = val;
}

// atomic-free CSR fill: col[row_ptr[dst]+rank] = src
__global__ void fill_csr_kernel(const int* __restrict__ src, const int* __restrict__ dst,
                                const int* __restrict__ rank, const int* __restrict__ row_ptr,
                                int* __restrict__ col, int E) {
    int e = blockIdx.x * blockDim.x + threadIdx.x;
    if (e < E) {
        col[row_ptr[dst[e]] + rank[e]] = src[e];
    }
}

// zero the sentinel rows (node N) of tmp chunks + q[N]
__global__ void zsent_kernel(float* __restrict__ tmp, float* __restrict__ q, int N, int N1) {
    int l = threadIdx.x;   // 64
    int c = l >> 4, f = l & 15;
    tmp[((size_t)c * N1 + N) * CF + f] = 0.0f;
    if (l == 0) q[N] = 0.0f;
}

// ---------- embW = emb @ W0 ----------
__global__ __launch_bounds__(256) void embw_kernel(const float* __restrict__ emb,
                                                   const float* __restrict__ W,
                                                   float* __restrict__ embW, int V) {
    __shared__ float Wsh[HIDDEN * HIDDEN];
    for (int i = threadIdx.x; i < HIDDEN * HIDDEN; i += blockDim.x) Wsh[i] = W[i];
    __syncthreads();
    int lane = threadIdx.x & 63;
    int v = blockIdx.x * 4 + (threadIdx.x >> 6);
    if (v >= V) return;
    float rv = emb[(size_t)v * HIDDEN + lane];
    float o = 0.0f;
#pragma unroll
    for (int k = 0; k < HIDDEN; k++) o = fmaf(__shfl(rv, k, 64), Wsh[k * HIDDEN + lane], o);
    embW[(size_t)v * HIDDEN + lane] = o;
}

// ---------- w~ = W2 @ Wreg ; wt[64] = b2 . Wreg ----------
__global__ void wtilde_kernel(const float* __restrict__ W2, const float* __restrict__ Wreg,
                              const float* __restrict__ b2, float* __restrict__ wt) {
    int k = threadIdx.x;
    float s = 0.0f;
    for (int j = 0; j < HIDDEN; j++) s += W2[k * HIDDEN + j] * Wreg[j];
    wt[k] = s;
    float cv = b2[k] * Wreg[k];
#pragma unroll
    for (int off = 32; off > 0; off >>= 1) cv += __shfl_down(cv, off, 64);
    if (k == 0) wt[HIDDEN] = cv;
}

// ---------- gather1: tmp[c][n][f] = embW[feats[n]][c*16+f] * nsrc[n] ----------
__global__ void gather1_kernel(const int* __restrict__ feats, const float* __restrict__ embW,
                               const float* __restrict__ nsrc, float* __restrict__ hT,
                               int N, int N1, int total) {
    int idx = blockIdx.x * blockDim.x + threadIdx.x;
    if (idx >= total) return;
    int c = idx / (N * CF);
    int r = idx - c * (N * CF);
    int n = r >> 4;
    int f = r & 15;
    hT[((size_t)c * N1 + n) * CF + f] = embW[feats[n] * HIDDEN + c * CF + f] * nsrc[n];
}

// ---------- dense 64x64 layer, chunked CF16 in/out, 2-node ILP ----------
__global__ __launch_bounds__(256) void dense_kernel(const float* __restrict__ inT,
                                                    const float* __restrict__ W,
                                                    float* __restrict__ outT,
                                                    int N, int N1, int nstride) {
    __shared__ float Wsh[HIDDEN * HIDDEN];
    for (int i = threadIdx.x; i < HIDDEN * HIDDEN; i += blockDim.x) Wsh[i] = W[i];
    __syncthreads();

    int lane = threadIdx.x & 63;
    int warp = threadIdx.x >> 6;
    size_t rowoff = (size_t)(lane >> 4) * N1;   // chunk base row
    int f = lane & 15;

    for (int n0 = blockIdx.x * 4 + warp; n0 < N; n0 += 2 * nstride) {
        int n1 = n0 + nstride;
        float rv0 = inT[(rowoff + n0) * CF + f];
        float rv1 = (n1 < N) ? inT[(rowoff + n1) * CF + f] : 0.0f;
        float o0 = 0.0f, o1 = 0.0f;
#pragma unroll
        for (int k = 0; k < HIDDEN; k++) {
            float w = Wsh[k * HIDDEN + lane];
            o0 = fmaf(__shfl(rv0, k, 64), w, o0);
            o1 = fmaf(__shfl(rv1, k, 64), w, o1);
        }
        outT[(rowoff + n0) * CF + f] = o0;
        if (n1 < N) outT[(rowoff + n1) * CF + f] = o1;
    }
}

// ---------- chunked gather-SpMM: padded CSR, float4, 2-node interleave ----------
__global__ __launch_bounds__(256) void spmm_kernel(const int* __restrict__ row_ptr,
                                                   const int* __restrict__ col,
                                                   const float* __restrict__ tmpT,
                                                   const float* __restrict__ ndst,
                                                   const float* __restrict__ nsrc,
                                                   const float* __restrict__ b,
                                                   float* __restrict__ outT,
                                                   int N, int N1, int nstride) {
    int lane = threadIdx.x & 63;
    int warp = threadIdx.x >> 6;
    int c = blockIdx.x & 3;
    int e = lane >> 2;
    int fq = lane & 3;
    const float* __restrict__ chunk = tmpT + (size_t)c * N1 * CF;
    float4 bias = ((const float4*)(b + c * CF))[fq];

    int start = (blockIdx.x >> 2) * 4 + warp;
    for (int n0 = start; n0 < N; n0 += 2 * nstride) {
        int n1 = n0 + nstride;
        int beg0 = row_ptr[n0], end0 = row_ptr[n0 + 1];
        int beg1 = 0, end1 = 0;
        if (n1 < N) { beg1 = row_ptr[n1]; end1 = row_ptr[n1 + 1]; }
        float4 acc0 = make_float4(0.f, 0.f, 0.f, 0.f);
        float4 acc1 = make_float4(0.f, 0.f, 0.f, 0.f);
        int j0 = beg0 + e, j1 = beg1 + e;
        while (j0 < end0 && j1 < end1) {
            int s0 = col[j0], s1 = col[j1];
            float4 v0 = *(const float4*)(chunk + (size_t)s0 * CF + fq * 4);
            float4 v1 = *(const float4*)(chunk + (size_t)s1 * CF + fq * 4);
            acc0.x += v0.x; acc0.y += v0.y; acc0.z += v0.z; acc0.w += v0.w;
            acc1.x += v1.x; acc1.y += v1.y; acc1.z += v1.z; acc1.w += v1.w;
            j0 += 16; j1 += 16;
        }
        while (j0 < end0) {
            int s0 = col[j0];
            float4 v0 = *(const float4*)(chunk + (size_t)s0 * CF + fq * 4);
            acc0.x += v0.x; acc0.y += v0.y; acc0.z += v0.z; acc0.w += v0.w;
            j0 += 16;
        }
        while (j1 < end1) {
            int s1 = col[j1];
            float4 v1 = *(const float4*)(chunk + (size_t)s1 * CF + fq * 4);
            acc1.x += v1.x; acc1.y += v1.y; acc1.z += v1.z; acc1.w += v1.w;
            j1 += 16;
        }
#pragma unroll
        for (int m = 4; m < 64; m <<= 1) {
            acc0.x += __shfl_xor(acc0.x, m, 64); acc0.y += __shfl_xor(acc0.y, m, 64);
            acc0.z += __shfl_xor(acc0.z, m, 64); acc0.w += __shfl_xor(acc0.w, m, 64);
            acc1.x += __shfl_xor(acc1.x, m, 64); acc1.y += __shfl_xor(acc1.y, m, 64);
            acc1.z += __shfl_xor(acc1.z, m, 64); acc1.w += __shfl_xor(acc1.w, m, 64);
        }
        if (e == 0) {
            float nd = ndst[n0], ns = nsrc[n0];
            float4 o;
            o.x = (acc0.x * nd + bias.x) * ns;
            o.y = (acc0.y * nd + bias.y) * ns;
            o.z = (acc0.z * nd + bias.z) * ns;
            o.w = (acc0.w * nd + bias.w) * ns;
            *(float4*)(outT + ((size_t)c * N1 + n0) * CF + fq * 4) = o;
            if (n1 < N) {
                nd = ndst[n1]; ns = nsrc[n1];
                o.x = (acc1.x * nd + bias.x) * ns;
                o.y = (acc1.y * nd + bias.y) * ns;
                o.z = (acc1.z * nd + bias.z) * ns;
                o.w = (acc1.w * nd + bias.w) * ns;
                *(float4*)(outT + ((size_t)c * N1 + n1) * CF + fq * 4) = o;
            }
        }
    }
}

// ---------- q[n] = hT[n] . w~ ----------
__global__ __launch_bounds__(256) void qdot_kernel(const float* __restrict__ hT,
                                                   const float* __restrict__ wt,
                                                   float* __restrict__ q, int N, int N1) {
    int lane = threadIdx.x & 63;
    int warp = threadIdx.x >> 6;
    int ns_ = lane >> 4, f = lane & 15;
    int n = (blockIdx.x * 4 + warp) * 4 + ns_;
    float acc = 0.0f;
#pragma unroll
    for (int c = 0; c < NCHUNK; c++) {
        float v = (n < N) ? hT[((size_t)c * N1 + n) * CF + f] : 0.0f;
        acc += v * wt[c * CF + f];
    }
    acc += __shfl_xor(acc, 1, 64);
    acc += __shfl_xor(acc, 2, 64);
    acc += __shfl_xor(acc, 4, 64);
    acc += __shfl_xor(acc, 8, 64);
    if (f == 0 && n < N) q[n] = acc;
}

// ---------- layer-3 scalar gather (padded CSR, 16 lanes/node) ----------
__global__ __launch_bounds__(256) void spmm3_kernel(const int* __restrict__ row_ptr,
                                                    const int* __restrict__ col,
                                                    const float* __restrict__ q,
                                                    const float* __restrict__ ndst,
                                                    float* __restrict__ nodeval, int N) {
    int lane = threadIdx.x & 63;
    int warp = threadIdx.x >> 6;
    int ns_ = lane >> 4, ln = lane & 15;
    int n = blockIdx.x * 16 + warp * 4 + ns_;
    if (n >= N) return;
    int beg = row_ptr[n], end = row_ptr[n + 1];
    float acc = 0.0f;
    for (int j = beg + ln; j < end; j += 16) acc += q[col[j]];
    acc += __shfl_xor(acc, 1, 64);
    acc += __shfl_xor(acc, 2, 64);
    acc += __shfl_xor(acc, 4, 64);
    acc += __shfl_xor(acc, 8, 64);
    if (ln == 0) nodeval[n] = acc * ndst[n];
}

// ---------- final: segmented sum over sorted gids ----------
__global__ __launch_bounds__(256) void final_kernel(const int* __restrict__ gids,
                                                    const float* __restrict__ nodeval,
                                                    const float* __restrict__ wt,
                                                    float* __restrict__ out, int N) {
    int n = blockIdx.x * 256 + threadIdx.x;
    int lane = threadIdx.x & 63;
    float c3 = wt[HIDDEN];
    float v = 0.0f;
    int g = -1;
    if (n < N) { v = nodeval[n] + c3; g = gids[n]; }
#pragma unroll
    for (int off = 1; off < 64; off <<= 1) {
        float u = __shfl_up(v, off, 64);
        int gu = __shfl_up(g, off, 64);
        if (lane >= off && gu == g) v += u;
    }
    int gn = __shfl_down(g, 1, 64);
    bool last = (lane == 63) || (gn != g);
    if (n < N && last) atomicAdd(&out[g], v);
}

extern "C" void kernel_launch(void* const* d_in, const int* in_sizes, int n_in,
                              void* d_out, int out_size, void* d_ws, size_t ws_size,
                              hipStream_t stream) {
    const int*   feats = (const int*)d_in[0];
    const int*   src   = (const int*)d_in[1];
    const int*   dst   = (const int*)d_in[2];
    const int*   gids  = (const int*)d_in[3];
    const float* emb   = (const float*)d_in[5];
    const float* Ws    = (const float*)d_in[6];
    const float* bs    = (const float*)d_in[7];
    const float* Wreg  = (const float*)d_in[8];
    float* out = (float*)d_out;

    int N = in_sizes[0];
    int E = in_sizes[1];
    int V = in_sizes[5] / HIDDEN;
    int N1 = N + 1;                 // +1 sentinel row per chunk
    int NB = (N + 255) / 256;
    int Ecap = E + 15 * N;          // upper bound on padded edge count

    char* p = (char*)d_ws;
    int*   outdeg  = (int*)p;    p += (size_t)N * 4;   // zeroed
    int*   cursor  = (int*)p;    p += (size_t)N * 4;   // zeroed (ends = indeg)
    float* nsrc    = (float*)p;  p += (size_t)N * 4;
    float* ndst    = (float*)p;  p += (size_t)N * 4;
    int*   rank    = (int*)p;    p += (size_t)E * 4;
    int*   row_ptr = (int*)p;    p += (size_t)(N + 1) * 4;
    int*   bsum    = (int*)p;    p += 1024 * 4;
    float* wt      = (float*)p;  p += (HIDDEN + 1) * 4;
    float* q       = (float*)p;  p += (size_t)(N + 1) * 4;   // + sentinel
    float* nodeval = (float*)p;  p += (size_t)N * 4;
    int*   col     = (int*)p;    p += (size_t)Ecap * 4;
    p = (char*)(((uintptr_t)p + 255) & ~(uintptr_t)255);
    float* embW    = (float*)p;  p += (size_t)V * HIDDEN * 4;
    float* hbuf    = (float*)p;  p += (size_t)N1 * HIDDEN * 4;   // CF16 chunked
    float* tmp     = (float*)p;  p += (size_t)N1 * HIDDEN * 4;   // CF16 chunked

    hipMemsetAsync(outdeg, 0, (size_t)N * 8, stream);        // outdeg + cursor
    hipMemsetAsync(out, 0, (size_t)out_size * 4, stream);

    zsent_kernel<<<1, 64, 0, stream>>>(tmp, q, N, N1);
    rank_kernel<<<(E + 255) / 256, 256, 0, stream>>>(src, dst, outdeg, cursor, rank, E);
    norm_bsum_kernel<<<NB, 256, 0, stream>>>(outdeg, cursor, nsrc, ndst, bsum, N);
    scan_bsum_kernel<<<1, 1024, 0, stream>>>(bsum, NB);
    scan_final_kernel<<<NB, 256, 0, stream>>>(cursor, bsum, row_ptr, N);
    fill_col_kernel<<<(Ecap + 255) / 256, 256, 0, stream>>>(col, N, Ecap);
    fill_csr_kernel<<<(E + 255) / 256, 256, 0, stream>>>(src, dst, rank, row_ptr, col, E);

    embw_kernel<<<(V + 3) / 4, 256, 0, stream>>>(emb, Ws + 0 * HIDDEN * HIDDEN, embW, V);
    wtilde_kernel<<<1, 64, 0, stream>>>(Ws + 2 * HIDDEN * HIDDEN, Wreg, bs + 2 * HIDDEN, wt);

    int total = N * HIDDEN;
    gather1_kernel<<<(total + 255) / 256, 256, 0, stream>>>(feats, embW, nsrc, tmp, N, N1, total);

    const int GB_SPMM = 2048;             // block groups per chunk
    const int GB_DENSE = 2048;
    int sstride = GB_SPMM * 4;
    int dstride = GB_DENSE * 4;

    // layer 1: hbuf = ((A tmp)*ndst + b0)*nsrc
    spmm_kernel<<<NCHUNK * GB_SPMM, 256, 0, stream>>>(row_ptr, col, tmp, ndst, nsrc,
                                                      bs + 0 * HIDDEN, hbuf, N, N1, sstride);
    // layer 2: tmp = hbuf @ W1 ; hbuf = ((A tmp)*ndst + b1)*nsrc
    dense_kernel<<<GB_DENSE, 256, 0, stream>>>(hbuf, Ws + 1 * HIDDEN * HIDDEN, tmp, N, N1, dstride);
    spmm_kernel<<<NCHUNK * GB_SPMM, 256, 0, stream>>>(row_ptr, col, tmp, ndst, nsrc,
                                                      bs + 1 * HIDDEN, hbuf, N, N1, sstride);
    // collapsed layer 3
    qdot_kernel<<<(N + 15) / 16, 256, 0, stream>>>(hbuf, wt, q, N, N1);
    spmm3_kernel<<<(N + 15) / 16, 256, 0, stream>>>(row_ptr, col, q, ndst, nodeval, N);
    final_kernel<<<NB, 256, 0, stream>>>(gids, nodeval, wt, out, N);
}